// Round 2
// baseline (270.696 us; speedup 1.0000x reference)
//
#include <hip/hip_runtime.h>
#include <math.h>

#define MEMSZ 16384
#define NCTX  16453   // MEM + 5 + 64

typedef float f4 __attribute__((ext_vector_type(4)));

// ---- soft-gate helpers (exact float32 replication of the reference) ----
__device__ __forceinline__ float sigmoidf_(float x) {
    return 1.0f / (1.0f + __expf(-x));
}
__device__ __forceinline__ float siluf_(float x) {
    return x * sigmoidf_(x);
}
// silu_threshold(x, 20) = (silu(20x+10) - silu(20x-10)) / 20
__device__ __forceinline__ float silu_thr(float x) {
    float d = 20.0f * x;
    return (siluf_(d + 10.0f) - siluf_(d - 10.0f)) * 0.05f;
}
// eq_gate(a,b) = st(diff+0.5) * st(-diff+0.5)
__device__ __forceinline__ float eq_gate_d(float diff) {
    return silu_thr(diff + 0.5f) * silu_thr(0.5f - diff);
}

// ---- fused: stage row in LDS, simulate, write back ----
// grid = B blocks, 256 threads. One row (64 KB) per block.
__global__ __launch_bounds__(256) void fused_sim_kernel(
        const float* __restrict__ memory,  // [B, MEMSZ]
        const float* __restrict__ outp,    // [B, 64]
        const float* __restrict__ ax_in,   // [B]
        const int*   __restrict__ pc_in,   // [B]
        const int*   __restrict__ sp_in,   // [B]
        const int*   __restrict__ bp_in,   // [B]
        const int*   __restrict__ ol_in,   // [B]
        const int*   __restrict__ nstep,   // [1]
        float*       __restrict__ dst)     // [B, MEMSZ] (d_out)
{
    __shared__ float smem[MEMSZ];          // 64 KiB row buffer

    const int b   = blockIdx.x;
    const int tid = threadIdx.x;

    const f4* __restrict__ src4 = (const f4*)(memory + (size_t)b * MEMSZ);
    f4*       __restrict__ dst4 = (f4*)(dst + (size_t)b * MEMSZ);
    f4*       sm4               = (f4*)smem;

    // ---- global -> LDS stage: 4096 float4 over 256 threads = 16 each ----
#pragma unroll
    for (int i = 0; i < 16; ++i) {
        sm4[tid + i * 256] = __builtin_nontemporal_load(&src4[tid + i * 256]);
    }
    __syncthreads();

    // ---- serial 16-step sim on LDS (thread 0; identical math/order to the
    //      verified absmax==0.0 kernel, only mrow -> smem) ----
    if (tid == 0) {
        const float* __restrict__ orow = outp + (size_t)b * 64;

        float pc  = (float)pc_in[b];
        float sp  = (float)sp_in[b];
        float bp  = (float)bp_in[b];
        float ax  = ax_in[b];
        float olf = (float)ol_in[b];
        int   T   = nstep[0];

        // OP_VALS order: IMM,LEA,ADD,SUB,MUL,DIV,MOD,SHL,SHR,EQ,NE,LT,GT,LE,GE
        const float opv[15] = {1.f, 2.f, 9.f, 10.f, 11.f, 12.f, 13.f, 14.f, 15.f,
                               3.f, 4.f, 5.f, 6.f, 7.f, 8.f};

        for (int t = 0; t < T; ++t) {
            // both gather addresses are known at step start: issue the two
            // ds_reads back-to-back so their latencies overlap
            float a1 = fminf(fmaxf(pc, 0.0f), (float)(NCTX - 1));
            int   ai = (int)a1;
            float a2 = fminf(fmaxf(sp, 0.0f), (float)(NCTX - 1));
            int   si = (int)a2;
            int pidx   = (ai < MEMSZ) ? ai : (ai - MEMSZ);
            int target = (si < MEMSZ) ? si : (si - MEMSZ);
            float m_pc = smem[pidx];
            float mtv  = smem[target];

            // ---------- inst = attend(context, pc) ----------
            float inst;
            if (ai < MEMSZ) {
                inst = m_pc;
            } else {
                int r = ai - MEMSZ;
                float cv = (r == 0) ? pc
                         : (r == 1) ? sp
                         : (r == 2) ? bp
                         : (r == 3) ? ax
                         : (r == 4) ? olf
                                    : orow[r - 5];
                // softmax ties 0.5/0.5 between slot ai and memory slot ai-MEM
                inst = 0.5f * (cv + m_pc);
            }
            float imm = floorf(inst * (1.0f / 256.0f));
            float opc = inst - imm * 256.0f;

            // ---------- stack_top = attend(context, sp) ----------
            float stv, wfac;
            if (si < MEMSZ) {
                stv = mtv;
                wfac = 1.0f;
            } else {
                int r = si - MEMSZ;
                float cv = (r == 0) ? pc
                         : (r == 1) ? sp
                         : (r == 2) ? bp
                         : (r == 3) ? ax
                         : (r == 4) ? olf
                                    : orow[r - 5];
                stv = 0.5f * (cv + mtv);
                wfac = 0.5f;
            }

            // ---------- experts ----------
            float a = stv, bv = ax;
            float safeb = (fabsf(bv) < 1e-6f) ? 1e-6f : bv;
            float dvv = a / safeb;
            float md  = a - safeb * floorf(dvv);
            float sh  = fminf(fmaxf(bv, 0.0f), 31.0f);
            float eq  = eq_gate_d(a - bv);
            float lt  = sigmoidf_(20.0f * (bv - a - 0.5f));
            float gt  = sigmoidf_(20.0f * (a - bv - 0.5f));
            float outs[15] = {
                imm,                 // IMM
                bp + imm,            // LEA
                a + bv,              // ADD
                a - bv,              // SUB
                a * bv,              // MUL
                dvv,                 // DIV
                md,                  // MOD
                a * exp2f(sh),       // SHL
                a * exp2f(-sh),      // SHR
                eq,                  // EQ
                1.0f - eq,           // NE
                lt,                  // LT
                gt,                  // GT
                1.0f - gt,           // LE
                1.0f - lt            // GE
            };

            float gsum = 0.0f, acc = 0.0f, pop = 0.0f;
#pragma unroll
            for (int j = 0; j < 15; ++j) {
                float g = eq_gate_d(opc - opv[j]);
                gsum += g;
                acc  += g * outs[j];
                if (j >= 2) pop += g;   // POP_MASK: everything except IMM, LEA
            }
            float nax = acc + (1.0f - gsum) * ax;

            // ---------- soft scatter (one-hot / half-weight) ----------
            smem[target] = mtv + pop * wfac * (nax - mtv);

            sp = sp + 8.0f * pop;
            pc = pc + 8.0f;
            ax = nax;
        }
    }
    __syncthreads();

    // ---- LDS -> global write-back ----
#pragma unroll
    for (int i = 0; i < 16; ++i) {
        __builtin_nontemporal_store(sm4[tid + i * 256], &dst4[tid + i * 256]);
    }
}

extern "C" void kernel_launch(void* const* d_in, const int* in_sizes, int n_in,
                              void* d_out, int out_size, void* d_ws, size_t ws_size,
                              hipStream_t stream) {
    const float* memory = (const float*)d_in[0];
    const float* output = (const float*)d_in[1];
    const float* ax     = (const float*)d_in[2];
    const int*   pc     = (const int*)d_in[3];
    const int*   sp     = (const int*)d_in[4];
    const int*   bp     = (const int*)d_in[5];
    const int*   ol     = (const int*)d_in[6];
    const int*   ns     = (const int*)d_in[7];

    int B = in_sizes[0] / MEMSZ;

    hipLaunchKernelGGL(fused_sim_kernel, dim3(B), dim3(256), 0, stream,
                       memory, output, ax, pc, sp, bp, ol, ns, (float*)d_out);
}

// Round 3
// 158.193 us; speedup vs baseline: 1.7112x; 1.7112x over previous
//
#include <hip/hip_runtime.h>
#include <math.h>

#define MEMSZ 16384
#define NCTX  16453   // MEM + 5 + 64

typedef float f4 __attribute__((ext_vector_type(4)));

// ---- soft-gate helpers ----
// v_rcp_f32-based sigmoid: ~1 ulp vs IEEE div, ~6x fewer instructions.
__device__ __forceinline__ float sigmoidf_(float x) {
    return __builtin_amdgcn_rcpf(1.0f + __expf(-x));
}
__device__ __forceinline__ float siluf_(float x) {
    return x * sigmoidf_(x);
}
// silu_threshold(x, 20) = (silu(20x+10) - silu(20x-10)) / 20
__device__ __forceinline__ float silu_thr(float x) {
    float d = 20.0f * x;
    return (siluf_(d + 10.0f) - siluf_(d - 10.0f)) * 0.05f;
}
// eq_gate(a,b) = st(diff+0.5) * st(-diff+0.5)
__device__ __forceinline__ float eq_gate_d(float diff) {
    return silu_thr(diff + 0.5f) * silu_thr(0.5f - diff);
}

// ---- bulk copy: memory -> d_out (full-BW streaming) ----
__global__ __launch_bounds__(256) void copy_kernel(const f4* __restrict__ src,
                                                   f4* __restrict__ dst, int n4) {
    int i = blockIdx.x * blockDim.x + threadIdx.x;
    if (i < n4)
        __builtin_nontemporal_store(__builtin_nontemporal_load(&src[i]), &dst[i]);
}

// ---- SIMT-over-rows simulator: 64 rows per wave, 1 wave per block.
//      16 blocks spread across 16 CUs; VALU issue amortized over 64 lanes. ----
__global__ __launch_bounds__(64) void sim_kernel(
        float* __restrict__ mem,          // [B, MEMSZ] (d_out, pre-copied)
        const float* __restrict__ outp,   // [B, 64]
        const float* __restrict__ ax_in,  // [B]
        const int* __restrict__ pc_in,    // [B]
        const int* __restrict__ sp_in,    // [B]
        const int* __restrict__ bp_in,    // [B]
        const int* __restrict__ ol_in,    // [B]
        const int* __restrict__ nstep,    // [1]
        int B) {
    int b = blockIdx.x * 64 + threadIdx.x;
    if (b >= B) return;

    float* __restrict__ mrow = mem + (size_t)b * MEMSZ;
    const float* __restrict__ orow = outp + (size_t)b * 64;

    float pc  = (float)pc_in[b];
    float sp  = (float)sp_in[b];
    float bp  = (float)bp_in[b];
    float ax  = ax_in[b];
    float olf = (float)ol_in[b];
    int   T   = nstep[0];

    // OP_VALS order: IMM,LEA,ADD,SUB,MUL,DIV,MOD,SHL,SHR,EQ,NE,LT,GT,LE,GE
    const float opv[15] = {1.f, 2.f, 9.f, 10.f, 11.f, 12.f, 13.f, 14.f, 15.f,
                           3.f, 4.f, 5.f, 6.f, 7.f, 8.f};

    for (int t = 0; t < T; ++t) {
        // both gather addresses known at step start: loads issue together
        float a1 = fminf(fmaxf(pc, 0.0f), (float)(NCTX - 1));
        int   ai = (int)a1;
        float a2 = fminf(fmaxf(sp, 0.0f), (float)(NCTX - 1));
        int   si = (int)a2;
        int pidx   = (ai < MEMSZ) ? ai : (ai - MEMSZ);
        int target = (si < MEMSZ) ? si : (si - MEMSZ);
        float m_pc = mrow[pidx];
        float mtv  = mrow[target];

        // ---------- inst = attend(context, pc) ----------
        float inst;
        if (ai < MEMSZ) {
            inst = m_pc;
        } else {
            int r = ai - MEMSZ;
            float cv = (r == 0) ? pc
                     : (r == 1) ? sp
                     : (r == 2) ? bp
                     : (r == 3) ? ax
                     : (r == 4) ? olf
                                : orow[r - 5];
            // softmax ties 0.5/0.5 between slot ai and memory slot ai-MEM
            inst = 0.5f * (cv + m_pc);
        }
        float imm = floorf(inst * (1.0f / 256.0f));
        float opc = inst - imm * 256.0f;

        // ---------- stack_top = attend(context, sp) ----------
        float stv, wfac;
        if (si < MEMSZ) {
            stv = mtv;
            wfac = 1.0f;
        } else {
            int r = si - MEMSZ;
            float cv = (r == 0) ? pc
                     : (r == 1) ? sp
                     : (r == 2) ? bp
                     : (r == 3) ? ax
                     : (r == 4) ? olf
                                : orow[r - 5];
            stv = 0.5f * (cv + mtv);
            wfac = 0.5f;
        }

        // ---------- experts ----------
        float a = stv, bv = ax;
        float safeb = (fabsf(bv) < 1e-6f) ? 1e-6f : bv;
        float dvv = a / safeb;          // keep IEEE: feeds floor (boundary-sensitive)
        float md  = a - safeb * floorf(dvv);
        float sh  = fminf(fmaxf(bv, 0.0f), 31.0f);
        float eq  = eq_gate_d(a - bv);
        float lt  = sigmoidf_(20.0f * (bv - a - 0.5f));
        float gt  = sigmoidf_(20.0f * (a - bv - 0.5f));
        float outs[15] = {
            imm,                 // IMM
            bp + imm,            // LEA
            a + bv,              // ADD
            a - bv,              // SUB
            a * bv,              // MUL
            dvv,                 // DIV
            md,                  // MOD
            a * exp2f(sh),       // SHL
            a * exp2f(-sh),      // SHR
            eq,                  // EQ
            1.0f - eq,           // NE
            lt,                  // LT
            gt,                  // GT
            1.0f - gt,           // LE
            1.0f - lt            // GE
        };

        float gsum = 0.0f, acc = 0.0f, pop = 0.0f;
#pragma unroll
        for (int j = 0; j < 15; ++j) {
            float g = eq_gate_d(opc - opv[j]);
            gsum += g;
            acc  += g * outs[j];
            if (j >= 2) pop += g;   // POP_MASK: everything except IMM, LEA
        }
        float nax = acc + (1.0f - gsum) * ax;

        // ---------- soft scatter (one-hot / half-weight) ----------
        mrow[target] = mtv + pop * wfac * (nax - mtv);

        sp = sp + 8.0f * pop;
        pc = pc + 8.0f;
        ax = nax;
    }
}

extern "C" void kernel_launch(void* const* d_in, const int* in_sizes, int n_in,
                              void* d_out, int out_size, void* d_ws, size_t ws_size,
                              hipStream_t stream) {
    const float* memory = (const float*)d_in[0];
    const float* output = (const float*)d_in[1];
    const float* ax     = (const float*)d_in[2];
    const int*   pc     = (const int*)d_in[3];
    const int*   sp     = (const int*)d_in[4];
    const int*   bp     = (const int*)d_in[5];
    const int*   ol     = (const int*)d_in[6];
    const int*   ns     = (const int*)d_in[7];

    int B = in_sizes[0] / MEMSZ;
    int n4 = (B * MEMSZ) / 4;

    hipLaunchKernelGGL(copy_kernel, dim3((n4 + 255) / 256), dim3(256), 0, stream,
                       (const f4*)memory, (f4*)d_out, n4);
    // 64 rows per wave (SIMT), one wave per block -> 16 blocks spread over CUs
    hipLaunchKernelGGL(sim_kernel, dim3((B + 63) / 64), dim3(64), 0, stream,
                       (float*)d_out, output, ax, pc, sp, bp, ol, ns, B);
}

// Round 5
// 156.416 us; speedup vs baseline: 1.7306x; 1.0114x over previous
//
#include <hip/hip_runtime.h>
#include <math.h>

#define MEMSZ 16384
#define NCTX  16453   // MEM + 5 + 64

typedef float f4 __attribute__((ext_vector_type(4)));

// ---- soft-gate helpers ----
// v_rcp_f32-based sigmoid: verified absmax==0.0 in round 3.
__device__ __forceinline__ float sigmoidf_(float x) {
    return __builtin_amdgcn_rcpf(1.0f + __expf(-x));
}
__device__ __forceinline__ float siluf_(float x) {
    return x * sigmoidf_(x);
}
// silu_threshold(x, 20) = (silu(20x+10) - silu(20x-10)) / 20
__device__ __forceinline__ float silu_thr(float x) {
    float d = 20.0f * x;
    return (siluf_(d + 10.0f) - siluf_(d - 10.0f)) * 0.05f;
}
// eq_gate(a,b) = st(diff+0.5) * st(-diff+0.5)
__device__ __forceinline__ float eq_gate_d(float diff) {
    return silu_thr(diff + 0.5f) * silu_thr(0.5f - diff);
}

// ---- bulk copy: memory -> d_out (full-BW streaming) ----
__global__ __launch_bounds__(256) void copy_kernel(const f4* __restrict__ src,
                                                   f4* __restrict__ dst, int n4) {
    int i = blockIdx.x * blockDim.x + threadIdx.x;
    if (i < n4)
        __builtin_nontemporal_store(__builtin_nontemporal_load(&src[i]), &dst[i]);
}

// ---- SIMT-over-rows simulator: 64 rows per wave, 1 wave per block. ----
// Fast path (T==16): pc-chain prefetched upfront (addresses are closed-form),
// sp-chain loads issued one step ahead (pop depends only on opc), both
// repaired against prior in-row stores via an in-register patch list.
// Patching is idempotent vs. completed stores, so values are exact.
__global__ __launch_bounds__(64) void sim_kernel(
        float* __restrict__ mem,          // [B, MEMSZ] (d_out, pre-copied)
        const float* __restrict__ outp,   // [B, 64]
        const float* __restrict__ ax_in,  // [B]
        const int* __restrict__ pc_in,    // [B]
        const int* __restrict__ sp_in,    // [B]
        const int* __restrict__ bp_in,    // [B]
        const int* __restrict__ ol_in,    // [B]
        const int* __restrict__ nstep,    // [1]
        int B) {
    int b = blockIdx.x * 64 + threadIdx.x;
    if (b >= B) return;

    float* __restrict__ mrow = mem + (size_t)b * MEMSZ;
    const float* __restrict__ orow = outp + (size_t)b * 64;

    float pc0 = (float)pc_in[b];
    float sp  = (float)sp_in[b];
    float bp  = (float)bp_in[b];
    float ax  = ax_in[b];
    float olf = (float)ol_in[b];
    int   T   = nstep[0];

    // OP_VALS order: IMM,LEA,ADD,SUB,MUL,DIV,MOD,SHL,SHR,EQ,NE,LT,GT,LE,GE
    const float opv[15] = {1.f, 2.f, 9.f, 10.f, 11.f, 12.f, 13.f, 14.f, 15.f,
                           3.f, 4.f, 5.f, 6.f, 7.f, 8.f};

    if (T == 16) {
        // ---- prefetch the 16 instruction-fetch cells (pc_t = pc0 + 8t exact) ----
        float pf[16];
        int   pfi[16];
#pragma unroll
        for (int t = 0; t < 16; ++t) {
            float pcr = pc0 + 8.0f * (float)t;
            float a1 = fminf(fmaxf(pcr, 0.0f), (float)(NCTX - 1));
            int ai = (int)a1;
            pfi[t] = ai;
            int pidx = (ai < MEMSZ) ? ai : ai - MEMSZ;
            pf[t] = mrow[pidx];           // 16 independent loads, one latency
        }

        // in-register store (patch) list
        int   sidx[16];
        float sval[16];
#pragma unroll
        for (int j = 0; j < 16; ++j) { sidx[j] = -1; sval[j] = 0.0f; }

        // first stack-top gather
        float a2 = fminf(fmaxf(sp, 0.0f), (float)(NCTX - 1));
        int   si  = (int)a2;
        int   tgt = (si < MEMSZ) ? si : si - MEMSZ;
        float raw = mrow[tgt];

#pragma unroll
        for (int t = 0; t < 16; ++t) {
            float pcr = pc0 + 8.0f * (float)t;   // == running pc (exact)

            // ---------- inst = attend(context, pc) ----------
            int ai   = pfi[t];
            int pidx = (ai < MEMSZ) ? ai : ai - MEMSZ;
            float m_pc = pf[t];
#pragma unroll
            for (int j = 0; j < 16; ++j)
                if (j < t && sidx[j] == pidx) m_pc = sval[j];

            float inst;
            if (ai < MEMSZ) {
                inst = m_pc;
            } else {
                int r = ai - MEMSZ;
                float cv = (r == 0) ? pcr
                         : (r == 1) ? sp
                         : (r == 2) ? bp
                         : (r == 3) ? ax
                         : (r == 4) ? olf
                                    : orow[r - 5];
                inst = 0.5f * (cv + m_pc);       // softmax 0.5/0.5 tie
            }
            float imm = floorf(inst * (1.0f / 256.0f));
            float opc = inst - imm * 256.0f;

            // ---------- gates (need only opc) ----------
            float g[15];
#pragma unroll
            for (int j = 0; j < 15; ++j) g[j] = eq_gate_d(opc - opv[j]);
            float gsum = 0.0f;
#pragma unroll
            for (int j = 0; j < 15; ++j) gsum += g[j];
            float pop = 0.0f;
#pragma unroll
            for (int j = 2; j < 15; ++j) pop += g[j];   // POP_MASK

            // ---------- lookahead: issue next step's stack-top load ----------
            float sp_next = sp + 8.0f * pop;
            int   si_n = 0, tgt_n = 0;
            float raw_n = 0.0f;
            if (t < 15) {
                float a2n = fminf(fmaxf(sp_next, 0.0f), (float)(NCTX - 1));
                si_n  = (int)a2n;
                tgt_n = (si_n < MEMSZ) ? si_n : si_n - MEMSZ;
                raw_n = mrow[tgt_n];     // latency hidden under expert ALU below
            }

            // ---------- stack_top (loaded last iter, patch-forwarded) ----------
            float mtv = raw;
#pragma unroll
            for (int j = 0; j < 16; ++j)
                if (j < t && sidx[j] == tgt) mtv = sval[j];

            float stv, wfac;
            if (si < MEMSZ) {
                stv = mtv;
                wfac = 1.0f;
            } else {
                int r = si - MEMSZ;
                float cv = (r == 0) ? pcr
                         : (r == 1) ? sp
                         : (r == 2) ? bp
                         : (r == 3) ? ax
                         : (r == 4) ? olf
                                    : orow[r - 5];
                stv = 0.5f * (cv + mtv);
                wfac = 0.5f;
            }

            // ---------- experts ----------
            float a = stv, bv = ax;
            float safeb = (fabsf(bv) < 1e-6f) ? 1e-6f : bv;
            float dvv = a / safeb;       // IEEE: feeds floor (boundary-sensitive)
            float md  = a - safeb * floorf(dvv);
            float sh  = fminf(fmaxf(bv, 0.0f), 31.0f);
            float eqg = eq_gate_d(a - bv);
            float lt  = sigmoidf_(20.0f * (bv - a - 0.5f));
            float gt  = sigmoidf_(20.0f * (a - bv - 0.5f));
            float outs[15] = {
                imm, bp + imm, a + bv, a - bv, a * bv, dvv, md,
                a * exp2f(sh), a * exp2f(-sh),
                eqg, 1.0f - eqg, lt, gt, 1.0f - gt, 1.0f - lt
            };
            float acc = 0.0f;
#pragma unroll
            for (int j = 0; j < 15; ++j) acc += g[j] * outs[j];
            float nax = acc + (1.0f - gsum) * ax;

            // ---------- soft scatter + record patch ----------
            float vnew = mtv + pop * wfac * (nax - mtv);
            mrow[tgt] = vnew;
            sidx[t] = tgt;
            sval[t] = vnew;

            sp = sp_next;
            ax = nax;
            if (t < 15) { si = si_n; tgt = tgt_n; raw = raw_n; }
        }
    } else {
        // ---- generic fallback: round-3 loop verbatim (any T) ----
        float pc = pc0;
        for (int t = 0; t < T; ++t) {
            float a1 = fminf(fmaxf(pc, 0.0f), (float)(NCTX - 1));
            int   ai = (int)a1;
            float a2 = fminf(fmaxf(sp, 0.0f), (float)(NCTX - 1));
            int   si = (int)a2;
            int pidx   = (ai < MEMSZ) ? ai : (ai - MEMSZ);
            int target = (si < MEMSZ) ? si : (si - MEMSZ);
            float m_pc = mrow[pidx];
            float mtv  = mrow[target];

            float inst;
            if (ai < MEMSZ) {
                inst = m_pc;
            } else {
                int r = ai - MEMSZ;
                float cv = (r == 0) ? pc
                         : (r == 1) ? sp
                         : (r == 2) ? bp
                         : (r == 3) ? ax
                         : (r == 4) ? olf
                                    : orow[r - 5];
                inst = 0.5f * (cv + m_pc);
            }
            float imm = floorf(inst * (1.0f / 256.0f));
            float opc = inst - imm * 256.0f;

            float stv, wfac;
            if (si < MEMSZ) {
                stv = mtv;
                wfac = 1.0f;
            } else {
                int r = si - MEMSZ;
                float cv = (r == 0) ? pc
                         : (r == 1) ? sp
                         : (r == 2) ? bp
                         : (r == 3) ? ax
                         : (r == 4) ? olf
                                    : orow[r - 5];
                stv = 0.5f * (cv + mtv);
                wfac = 0.5f;
            }

            float a = stv, bv = ax;
            float safeb = (fabsf(bv) < 1e-6f) ? 1e-6f : bv;
            float dvv = a / safeb;
            float md  = a - safeb * floorf(dvv);
            float sh  = fminf(fmaxf(bv, 0.0f), 31.0f);
            float eqg = eq_gate_d(a - bv);
            float lt  = sigmoidf_(20.0f * (bv - a - 0.5f));
            float gt  = sigmoidf_(20.0f * (a - bv - 0.5f));
            float outs[15] = {
                imm, bp + imm, a + bv, a - bv, a * bv, dvv, md,
                a * exp2f(sh), a * exp2f(-sh),
                eqg, 1.0f - eqg, lt, gt, 1.0f - gt, 1.0f - lt
            };

            float gsum = 0.0f, acc = 0.0f, pop = 0.0f;
#pragma unroll
            for (int j = 0; j < 15; ++j) {
                float gg = eq_gate_d(opc - opv[j]);
                gsum += gg;
                acc  += gg * outs[j];
                if (j >= 2) pop += gg;
            }
            float nax = acc + (1.0f - gsum) * ax;

            mrow[target] = mtv + pop * wfac * (nax - mtv);

            sp = sp + 8.0f * pop;
            pc = pc + 8.0f;
            ax = nax;
        }
    }
}

extern "C" void kernel_launch(void* const* d_in, const int* in_sizes, int n_in,
                              void* d_out, int out_size, void* d_ws, size_t ws_size,
                              hipStream_t stream) {
    const float* memory = (const float*)d_in[0];
    const float* output = (const float*)d_in[1];
    const float* ax     = (const float*)d_in[2];
    const int*   pc     = (const int*)d_in[3];
    const int*   sp     = (const int*)d_in[4];
    const int*   bp     = (const int*)d_in[5];
    const int*   ol     = (const int*)d_in[6];
    const int*   ns     = (const int*)d_in[7];

    int B = in_sizes[0] / MEMSZ;
    int n4 = (B * MEMSZ) / 4;

    hipLaunchKernelGGL(copy_kernel, dim3((n4 + 255) / 256), dim3(256), 0, stream,
                       (const f4*)memory, (f4*)d_out, n4);
    hipLaunchKernelGGL(sim_kernel, dim3((B + 63) / 64), dim3(64), 0, stream,
                       (float*)d_out, output, ax, pc, sp, bp, ol, ns, B);
}

// Round 6
// 147.031 us; speedup vs baseline: 1.8411x; 1.0638x over previous
//
#include <hip/hip_runtime.h>
#include <math.h>

#define MEMSZ 16384
#define NCTX  16453   // MEM + 5 + 64

typedef float f4 __attribute__((ext_vector_type(4)));

// ---- soft-gate helpers ----
// v_rcp_f32-based sigmoid: verified absmax==0.0 in rounds 3/5.
__device__ __forceinline__ float sigmoidf_(float x) {
    return __builtin_amdgcn_rcpf(1.0f + __expf(-x));
}
__device__ __forceinline__ float siluf_(float x) {
    return x * sigmoidf_(x);
}
// silu_threshold(x, 20) = (silu(20x+10) - silu(20x-10)) / 20
__device__ __forceinline__ float silu_thr(float x) {
    float d = 20.0f * x;
    return (siluf_(d + 10.0f) - siluf_(d - 10.0f)) * 0.05f;
}
// eq_gate(a,b) = st(diff+0.5) * st(-diff+0.5)
__device__ __forceinline__ float eq_gate_d(float diff) {
    return silu_thr(diff + 0.5f) * silu_thr(0.5f - diff);
}

// ---- bulk copy: memory -> d_out (full-BW streaming) ----
__global__ __launch_bounds__(256) void copy_kernel(const f4* __restrict__ src,
                                                   f4* __restrict__ dst, int n4) {
    int i = blockIdx.x * blockDim.x + threadIdx.x;
    if (i < n4)
        __builtin_nontemporal_store(__builtin_nontemporal_load(&src[i]), &dst[i]);
}

// ---- one ROW per WAVE simulator ----
// Lanes 0-14 compute the 15 opcode gates in parallel (per-lane opv constant,
// identical instruction sequence per gate -> identical bits). Everything else
// is wave-uniform (redundant on all 64 lanes). Gate values are gathered with
// compile-time-lane __shfl and reduced in the exact ascending-j order/
// expression form of the verified round-5 kernel.
__global__ __launch_bounds__(64) void sim_kernel(
        float* __restrict__ mem,          // [B, MEMSZ] (d_out, pre-copied)
        const float* __restrict__ outp,   // [B, 64]
        const float* __restrict__ ax_in,  // [B]
        const int* __restrict__ pc_in,    // [B]
        const int* __restrict__ sp_in,    // [B]
        const int* __restrict__ bp_in,    // [B]
        const int* __restrict__ ol_in,    // [B]
        const int* __restrict__ nstep,    // [1]
        int B) {
    int b = blockIdx.x;
    if (b >= B) return;
    int lane = threadIdx.x;

    float* __restrict__ mrow = mem + (size_t)b * MEMSZ;
    const float* __restrict__ orow = outp + (size_t)b * 64;

    float pc0 = (float)pc_in[b];
    float sp  = (float)sp_in[b];
    float bp  = (float)bp_in[b];
    float ax  = ax_in[b];
    float olf = (float)ol_in[b];
    int   T   = nstep[0];

    // per-lane gate opcode: OP_VALS[lane] for lane<15
    // OP_VALS: IMM=1,LEA=2,ADD=9,SUB=10,MUL=11,DIV=12,MOD=13,SHL=14,SHR=15,
    //          EQ=3,NE=4,LT=5,GT=6,LE=7,GE=8
    float opvl = (lane < 2)  ? (float)(lane + 1)
               : (lane < 9)  ? (float)(lane + 7)
               : (lane < 15) ? (float)(lane - 6)
                             : 0.0f;   // lanes 15-63: dummy, never read

    if (T == 16) {
        // ---- prefetch the 16 instruction-fetch cells (pc_t = pc0 + 8t exact);
        //      wave-uniform addresses -> one cache line per load ----
        float pf[16];
        int   pfi[16];
#pragma unroll
        for (int t = 0; t < 16; ++t) {
            float pcr = pc0 + 8.0f * (float)t;
            float a1 = fminf(fmaxf(pcr, 0.0f), (float)(NCTX - 1));
            int ai = (int)a1;
            pfi[t] = ai;
            int pidx = (ai < MEMSZ) ? ai : ai - MEMSZ;
            pf[t] = mrow[pidx];
        }

        // in-register store (patch) list, maintained uniformly on all lanes
        int   sidx[16];
        float sval[16];
#pragma unroll
        for (int j = 0; j < 16; ++j) { sidx[j] = -1; sval[j] = 0.0f; }

        // first stack-top gather
        float a2 = fminf(fmaxf(sp, 0.0f), (float)(NCTX - 1));
        int   si  = (int)a2;
        int   tgt = (si < MEMSZ) ? si : si - MEMSZ;
        float raw = mrow[tgt];

#pragma unroll
        for (int t = 0; t < 16; ++t) {
            float pcr = pc0 + 8.0f * (float)t;   // == running pc (exact)

            // ---------- inst = attend(context, pc) ----------
            int ai   = pfi[t];
            int pidx = (ai < MEMSZ) ? ai : ai - MEMSZ;
            float m_pc = pf[t];
#pragma unroll
            for (int j = 0; j < 16; ++j)
                if (j < t && sidx[j] == pidx) m_pc = sval[j];

            float inst;
            if (ai < MEMSZ) {
                inst = m_pc;
            } else {
                int r = ai - MEMSZ;
                float cv = (r == 0) ? pcr
                         : (r == 1) ? sp
                         : (r == 2) ? bp
                         : (r == 3) ? ax
                         : (r == 4) ? olf
                                    : orow[r - 5];
                inst = 0.5f * (cv + m_pc);       // softmax 0.5/0.5 tie
            }
            float imm = floorf(inst * (1.0f / 256.0f));
            float opc = inst - imm * 256.0f;

            // ---------- gates: one per lane, in parallel ----------
            float gl = eq_gate_d(opc - opvl);

            // gather lane 0-14 gate values to all lanes (compile-time lanes)
            float G0  = __shfl(gl, 0),  G1  = __shfl(gl, 1),  G2  = __shfl(gl, 2);
            float G3  = __shfl(gl, 3),  G4  = __shfl(gl, 4),  G5  = __shfl(gl, 5);
            float G6  = __shfl(gl, 6),  G7  = __shfl(gl, 7),  G8  = __shfl(gl, 8);
            float G9  = __shfl(gl, 9),  G10 = __shfl(gl, 10), G11 = __shfl(gl, 11);
            float G12 = __shfl(gl, 12), G13 = __shfl(gl, 13), G14 = __shfl(gl, 14);

            // ---------- gsum / pop (ascending j, exact round-5 order) ----------
            float gsum = 0.0f;
            gsum += G0;  gsum += G1;  gsum += G2;  gsum += G3;  gsum += G4;
            gsum += G5;  gsum += G6;  gsum += G7;  gsum += G8;  gsum += G9;
            gsum += G10; gsum += G11; gsum += G12; gsum += G13; gsum += G14;
            float pop = 0.0f;
            pop += G2;  pop += G3;  pop += G4;  pop += G5;  pop += G6;
            pop += G7;  pop += G8;  pop += G9;  pop += G10; pop += G11;
            pop += G12; pop += G13; pop += G14;

            // ---------- lookahead: issue next step's stack-top load ----------
            float sp_next = sp + 8.0f * pop;
            int   si_n = 0, tgt_n = 0;
            float raw_n = 0.0f;
            if (t < 15) {
                float a2n = fminf(fmaxf(sp_next, 0.0f), (float)(NCTX - 1));
                si_n  = (int)a2n;
                tgt_n = (si_n < MEMSZ) ? si_n : si_n - MEMSZ;
                raw_n = mrow[tgt_n];     // latency hidden under expert ALU below
            }

            // ---------- stack_top (loaded last iter, patch-forwarded) ----------
            float mtv = raw;
#pragma unroll
            for (int j = 0; j < 16; ++j)
                if (j < t && sidx[j] == tgt) mtv = sval[j];

            float stv, wfac;
            if (si < MEMSZ) {
                stv = mtv;
                wfac = 1.0f;
            } else {
                int r = si - MEMSZ;
                float cv = (r == 0) ? pcr
                         : (r == 1) ? sp
                         : (r == 2) ? bp
                         : (r == 3) ? ax
                         : (r == 4) ? olf
                                    : orow[r - 5];
                stv = 0.5f * (cv + mtv);
                wfac = 0.5f;
            }

            // ---------- experts (named scalars, uniform on all lanes) ----------
            float a = stv, bv = ax;
            float safeb = (fabsf(bv) < 1e-6f) ? 1e-6f : bv;
            float dvv = a / safeb;       // IEEE: feeds floor (boundary-sensitive)
            float md  = a - safeb * floorf(dvv);
            float sh  = fminf(fmaxf(bv, 0.0f), 31.0f);
            float eqg = eq_gate_d(a - bv);
            float lt  = sigmoidf_(20.0f * (bv - a - 0.5f));
            float gt  = sigmoidf_(20.0f * (a - bv - 0.5f));
            float o0 = imm,            o1 = bp + imm,     o2 = a + bv;
            float o3 = a - bv,         o4 = a * bv,       o5 = dvv;
            float o6 = md,             o7 = a * exp2f(sh), o8 = a * exp2f(-sh);
            float o9 = eqg,            o10 = 1.0f - eqg,  o11 = lt;
            float o12 = gt,            o13 = 1.0f - gt,   o14 = 1.0f - lt;

            // ---------- acc (ascending j, exact round-5 expression form) ----------
            float acc = 0.0f;
            acc += G0 * o0;   acc += G1 * o1;   acc += G2 * o2;
            acc += G3 * o3;   acc += G4 * o4;   acc += G5 * o5;
            acc += G6 * o6;   acc += G7 * o7;   acc += G8 * o8;
            acc += G9 * o9;   acc += G10 * o10; acc += G11 * o11;
            acc += G12 * o12; acc += G13 * o13; acc += G14 * o14;
            float nax = acc + (1.0f - gsum) * ax;

            // ---------- soft scatter + record patch ----------
            float vnew = mtv + pop * wfac * (nax - mtv);
            if (lane == 0) mrow[tgt] = vnew;
            sidx[t] = tgt;
            sval[t] = vnew;

            sp = sp_next;
            ax = nax;
            if (t < 15) { si = si_n; tgt = tgt_n; raw = raw_n; }
        }
    } else if (lane == 0) {
        // ---- generic fallback (any T): round-3 serial loop verbatim ----
        const float opv[15] = {1.f, 2.f, 9.f, 10.f, 11.f, 12.f, 13.f, 14.f, 15.f,
                               3.f, 4.f, 5.f, 6.f, 7.f, 8.f};
        float pc = pc0;
        for (int t = 0; t < T; ++t) {
            float a1 = fminf(fmaxf(pc, 0.0f), (float)(NCTX - 1));
            int   ai = (int)a1;
            float a2 = fminf(fmaxf(sp, 0.0f), (float)(NCTX - 1));
            int   si = (int)a2;
            int pidx   = (ai < MEMSZ) ? ai : (ai - MEMSZ);
            int target = (si < MEMSZ) ? si : (si - MEMSZ);
            float m_pc = mrow[pidx];
            float mtv  = mrow[target];

            float inst;
            if (ai < MEMSZ) {
                inst = m_pc;
            } else {
                int r = ai - MEMSZ;
                float cv = (r == 0) ? pc
                         : (r == 1) ? sp
                         : (r == 2) ? bp
                         : (r == 3) ? ax
                         : (r == 4) ? olf
                                    : orow[r - 5];
                inst = 0.5f * (cv + m_pc);
            }
            float imm = floorf(inst * (1.0f / 256.0f));
            float opc = inst - imm * 256.0f;

            float stv, wfac;
            if (si < MEMSZ) {
                stv = mtv;
                wfac = 1.0f;
            } else {
                int r = si - MEMSZ;
                float cv = (r == 0) ? pc
                         : (r == 1) ? sp
                         : (r == 2) ? bp
                         : (r == 3) ? ax
                         : (r == 4) ? olf
                                    : orow[r - 5];
                stv = 0.5f * (cv + mtv);
                wfac = 0.5f;
            }

            float a = stv, bv = ax;
            float safeb = (fabsf(bv) < 1e-6f) ? 1e-6f : bv;
            float dvv = a / safeb;
            float md  = a - safeb * floorf(dvv);
            float sh  = fminf(fmaxf(bv, 0.0f), 31.0f);
            float eqg = eq_gate_d(a - bv);
            float lt  = sigmoidf_(20.0f * (bv - a - 0.5f));
            float gt  = sigmoidf_(20.0f * (a - bv - 0.5f));
            float outs[15] = {
                imm, bp + imm, a + bv, a - bv, a * bv, dvv, md,
                a * exp2f(sh), a * exp2f(-sh),
                eqg, 1.0f - eqg, lt, gt, 1.0f - gt, 1.0f - lt
            };

            float gsum = 0.0f, acc = 0.0f, pop = 0.0f;
#pragma unroll
            for (int j = 0; j < 15; ++j) {
                float gg = eq_gate_d(opc - opv[j]);
                gsum += gg;
                acc  += gg * outs[j];
                if (j >= 2) pop += gg;
            }
            float nax = acc + (1.0f - gsum) * ax;

            mrow[target] = mtv + pop * wfac * (nax - mtv);

            sp = sp + 8.0f * pop;
            pc = pc + 8.0f;
            ax = nax;
        }
    }
}

extern "C" void kernel_launch(void* const* d_in, const int* in_sizes, int n_in,
                              void* d_out, int out_size, void* d_ws, size_t ws_size,
                              hipStream_t stream) {
    const float* memory = (const float*)d_in[0];
    const float* output = (const float*)d_in[1];
    const float* ax     = (const float*)d_in[2];
    const int*   pc     = (const int*)d_in[3];
    const int*   sp     = (const int*)d_in[4];
    const int*   bp     = (const int*)d_in[5];
    const int*   ol     = (const int*)d_in[6];
    const int*   ns     = (const int*)d_in[7];

    int B = in_sizes[0] / MEMSZ;
    int n4 = (B * MEMSZ) / 4;

    hipLaunchKernelGGL(copy_kernel, dim3((n4 + 255) / 256), dim3(256), 0, stream,
                       (const f4*)memory, (f4*)d_out, n4);
    // one row per wave: B blocks x 64 threads -> 1 wave per SIMD chip-wide
    hipLaunchKernelGGL(sim_kernel, dim3(B), dim3(64), 0, stream,
                       (float*)d_out, output, ax, pc, sp, bp, ol, ns, B);
}

// Round 7
// 138.972 us; speedup vs baseline: 1.9478x; 1.0580x over previous
//
#include <hip/hip_runtime.h>
#include <math.h>

#define MEMSZ 16384
#define NCTX  16453   // MEM + 5 + 64

typedef float f4 __attribute__((ext_vector_type(4)));

// ---- soft-gate helpers ----
// v_rcp_f32-based sigmoid: verified absmax==0.0 in rounds 3/5/6.
__device__ __forceinline__ float sigmoidf_(float x) {
    return __builtin_amdgcn_rcpf(1.0f + __expf(-x));
}
__device__ __forceinline__ float siluf_(float x) {
    return x * sigmoidf_(x);
}
// silu_threshold(x, 20) = (silu(20x+10) - silu(20x-10)) / 20
__device__ __forceinline__ float silu_thr(float x) {
    float d = 20.0f * x;
    return (siluf_(d + 10.0f) - siluf_(d - 10.0f)) * 0.05f;
}
// eq_gate(a,b) = st(diff+0.5) * st(-diff+0.5)
__device__ __forceinline__ float eq_gate_d(float diff) {
    return silu_thr(diff + 0.5f) * silu_thr(0.5f - diff);
}

// ---- fused copy+sim: one block per row, 256 threads (4 waves). ----
// Waves 1-3 stream the 64KB row input->d_out. Wave 0 concurrently runs the
// sim AGAINST THE INPUT ROW: every read is either an untouched input cell or
// a previously-stored cell, which the in-register patch list forwards exactly
// (round-5/6 machinery, verified absmax==0.0). After __syncthreads, lane 0
// applies the <=16 patches to d_out in ascending-t order (last write wins).
// Sim latency hides under the copy; copy waves give the sim wave TLP.
__global__ __launch_bounds__(256) void fused_kernel(
        const float* __restrict__ memory, // [B, MEMSZ] input
        const float* __restrict__ outp,   // [B, 64]
        const float* __restrict__ ax_in,  // [B]
        const int* __restrict__ pc_in,    // [B]
        const int* __restrict__ sp_in,    // [B]
        const int* __restrict__ bp_in,    // [B]
        const int* __restrict__ ol_in,    // [B]
        const int* __restrict__ nstep,    // [1]
        float* __restrict__ dst,          // [B, MEMSZ] (d_out)
        int B) {
    const int b   = blockIdx.x;
    const int tid = threadIdx.x;

    const float* __restrict__ mrow_in  = memory + (size_t)b * MEMSZ;
    float*       __restrict__ mrow_out = dst    + (size_t)b * MEMSZ;
    const f4* __restrict__ src4 = (const f4*)mrow_in;
    f4*       __restrict__ dst4 = (f4*)mrow_out;

    const int T = nstep[0];

    if (T == 16) {
        // patch list lives in wave-0 registers; declared here so the
        // post-sync patch-apply (also wave 0) sees it.
        int   sidx[16];
        float sval[16];

        if (tid >= 64) {
            // ---- copy waves: 192 lanes stream 4096 float4 ----
            int c = tid - 64;
#pragma unroll
            for (int i = 0; i < 22; ++i) {
                int idx = c + i * 192;
                if (idx < 4096)
                    __builtin_nontemporal_store(
                        __builtin_nontemporal_load(&src4[idx]), &dst4[idx]);
            }
        } else {
            // ---- sim wave (wave 0): reads input row + patch registers ----
            const int lane = tid;
            const float* __restrict__ orow = outp + (size_t)b * 64;

            float pc0 = (float)pc_in[b];
            float sp  = (float)sp_in[b];
            float bp  = (float)bp_in[b];
            float ax  = ax_in[b];
            float olf = (float)ol_in[b];

            // per-lane gate opcode: OP_VALS[lane] for lane<15
            // OP_VALS: IMM=1,LEA=2,ADD=9..SHR=15, EQ=3..GE=8
            float opvl = (lane < 2)  ? (float)(lane + 1)
                       : (lane < 9)  ? (float)(lane + 7)
                       : (lane < 15) ? (float)(lane - 6)
                                     : 0.0f;   // lanes 15-63: dummy

            // prefetch the 16 instruction-fetch cells (pc_t = pc0+8t exact)
            float pf[16];
            int   pfi[16];
#pragma unroll
            for (int t = 0; t < 16; ++t) {
                float pcr = pc0 + 8.0f * (float)t;
                float a1 = fminf(fmaxf(pcr, 0.0f), (float)(NCTX - 1));
                int ai = (int)a1;
                pfi[t] = ai;
                int pidx = (ai < MEMSZ) ? ai : ai - MEMSZ;
                pf[t] = mrow_in[pidx];
            }

#pragma unroll
            for (int j = 0; j < 16; ++j) { sidx[j] = -1; sval[j] = 0.0f; }

            // first stack-top gather
            float a2 = fminf(fmaxf(sp, 0.0f), (float)(NCTX - 1));
            int   si  = (int)a2;
            int   tgt = (si < MEMSZ) ? si : si - MEMSZ;
            float raw = mrow_in[tgt];

#pragma unroll
            for (int t = 0; t < 16; ++t) {
                float pcr = pc0 + 8.0f * (float)t;

                // ---------- inst = attend(context, pc) ----------
                int ai   = pfi[t];
                int pidx = (ai < MEMSZ) ? ai : ai - MEMSZ;
                float m_pc = pf[t];
#pragma unroll
                for (int j = 0; j < 16; ++j)
                    if (j < t && sidx[j] == pidx) m_pc = sval[j];

                float inst;
                if (ai < MEMSZ) {
                    inst = m_pc;
                } else {
                    int r = ai - MEMSZ;
                    float cv = (r == 0) ? pcr
                             : (r == 1) ? sp
                             : (r == 2) ? bp
                             : (r == 3) ? ax
                             : (r == 4) ? olf
                                        : orow[r - 5];
                    inst = 0.5f * (cv + m_pc);   // softmax 0.5/0.5 tie
                }
                float imm = floorf(inst * (1.0f / 256.0f));
                float opc = inst - imm * 256.0f;

                // ---------- gates: one per lane, in parallel ----------
                float gl = eq_gate_d(opc - opvl);
                float G0  = __shfl(gl, 0),  G1  = __shfl(gl, 1),  G2  = __shfl(gl, 2);
                float G3  = __shfl(gl, 3),  G4  = __shfl(gl, 4),  G5  = __shfl(gl, 5);
                float G6  = __shfl(gl, 6),  G7  = __shfl(gl, 7),  G8  = __shfl(gl, 8);
                float G9  = __shfl(gl, 9),  G10 = __shfl(gl, 10), G11 = __shfl(gl, 11);
                float G12 = __shfl(gl, 12), G13 = __shfl(gl, 13), G14 = __shfl(gl, 14);

                // gsum / pop (ascending j, exact verified order)
                float gsum = 0.0f;
                gsum += G0;  gsum += G1;  gsum += G2;  gsum += G3;  gsum += G4;
                gsum += G5;  gsum += G6;  gsum += G7;  gsum += G8;  gsum += G9;
                gsum += G10; gsum += G11; gsum += G12; gsum += G13; gsum += G14;
                float pop = 0.0f;
                pop += G2;  pop += G3;  pop += G4;  pop += G5;  pop += G6;
                pop += G7;  pop += G8;  pop += G9;  pop += G10; pop += G11;
                pop += G12; pop += G13; pop += G14;

                // ---------- lookahead: next step's stack-top load ----------
                float sp_next = sp + 8.0f * pop;
                int   si_n = 0, tgt_n = 0;
                float raw_n = 0.0f;
                if (t < 15) {
                    float a2n = fminf(fmaxf(sp_next, 0.0f), (float)(NCTX - 1));
                    si_n  = (int)a2n;
                    tgt_n = (si_n < MEMSZ) ? si_n : si_n - MEMSZ;
                    raw_n = mrow_in[tgt_n];
                }

                // ---------- stack_top (patch-forwarded) ----------
                float mtv = raw;
#pragma unroll
                for (int j = 0; j < 16; ++j)
                    if (j < t && sidx[j] == tgt) mtv = sval[j];

                float stv, wfac;
                if (si < MEMSZ) {
                    stv = mtv;
                    wfac = 1.0f;
                } else {
                    int r = si - MEMSZ;
                    float cv = (r == 0) ? pcr
                             : (r == 1) ? sp
                             : (r == 2) ? bp
                             : (r == 3) ? ax
                             : (r == 4) ? olf
                                        : orow[r - 5];
                    stv = 0.5f * (cv + mtv);
                    wfac = 0.5f;
                }

                // ---------- experts (uniform on all lanes) ----------
                float a = stv, bv = ax;
                float safeb = (fabsf(bv) < 1e-6f) ? 1e-6f : bv;
                float dvv = a / safeb;   // IEEE: feeds floor
                float md  = a - safeb * floorf(dvv);
                float sh  = fminf(fmaxf(bv, 0.0f), 31.0f);
                float eqg = eq_gate_d(a - bv);
                float lt  = sigmoidf_(20.0f * (bv - a - 0.5f));
                float gt  = sigmoidf_(20.0f * (a - bv - 0.5f));
                float o0 = imm,            o1 = bp + imm,      o2 = a + bv;
                float o3 = a - bv,         o4 = a * bv,        o5 = dvv;
                float o6 = md,             o7 = a * exp2f(sh), o8 = a * exp2f(-sh);
                float o9 = eqg,            o10 = 1.0f - eqg,   o11 = lt;
                float o12 = gt,            o13 = 1.0f - gt,    o14 = 1.0f - lt;

                // acc (ascending j, exact verified expression form)
                float acc = 0.0f;
                acc += G0 * o0;   acc += G1 * o1;   acc += G2 * o2;
                acc += G3 * o3;   acc += G4 * o4;   acc += G5 * o5;
                acc += G6 * o6;   acc += G7 * o7;   acc += G8 * o8;
                acc += G9 * o9;   acc += G10 * o10; acc += G11 * o11;
                acc += G12 * o12; acc += G13 * o13; acc += G14 * o14;
                float nax = acc + (1.0f - gsum) * ax;

                // ---------- record patch (no store yet) ----------
                float vnew = mtv + pop * wfac * (nax - mtv);
                sidx[t] = tgt;
                sval[t] = vnew;

                sp = sp_next;
                ax = nax;
                if (t < 15) { si = si_n; tgt = tgt_n; raw = raw_n; }
            }
        }

        __syncthreads();   // copy complete + patches final

        // ---- apply patches (ascending t: last write to an index wins) ----
        if (tid == 0) {
#pragma unroll
            for (int t = 0; t < 16; ++t)
                mrow_out[sidx[t]] = sval[t];
        }
    } else {
        // ---- generic fallback (any T): copy row, then serial sim on d_out ----
#pragma unroll
        for (int i = 0; i < 16; ++i)
            dst4[tid + i * 256] = src4[tid + i * 256];
        __syncthreads();

        if (tid == 0) {
            const float* __restrict__ orow = outp + (size_t)b * 64;
            const float opv[15] = {1.f, 2.f, 9.f, 10.f, 11.f, 12.f, 13.f, 14.f,
                                   15.f, 3.f, 4.f, 5.f, 6.f, 7.f, 8.f};
            float pc  = (float)pc_in[b];
            float sp  = (float)sp_in[b];
            float bp  = (float)bp_in[b];
            float ax  = ax_in[b];
            float olf = (float)ol_in[b];

            for (int t = 0; t < T; ++t) {
                float a1 = fminf(fmaxf(pc, 0.0f), (float)(NCTX - 1));
                int   ai = (int)a1;
                float a2 = fminf(fmaxf(sp, 0.0f), (float)(NCTX - 1));
                int   si = (int)a2;
                int pidx   = (ai < MEMSZ) ? ai : (ai - MEMSZ);
                int target = (si < MEMSZ) ? si : (si - MEMSZ);
                float m_pc = mrow_out[pidx];
                float mtv  = mrow_out[target];

                float inst;
                if (ai < MEMSZ) {
                    inst = m_pc;
                } else {
                    int r = ai - MEMSZ;
                    float cv = (r == 0) ? pc
                             : (r == 1) ? sp
                             : (r == 2) ? bp
                             : (r == 3) ? ax
                             : (r == 4) ? olf
                                        : orow[r - 5];
                    inst = 0.5f * (cv + m_pc);
                }
                float imm = floorf(inst * (1.0f / 256.0f));
                float opc = inst - imm * 256.0f;

                float stv, wfac;
                if (si < MEMSZ) {
                    stv = mtv;
                    wfac = 1.0f;
                } else {
                    int r = si - MEMSZ;
                    float cv = (r == 0) ? pc
                             : (r == 1) ? sp
                             : (r == 2) ? bp
                             : (r == 3) ? ax
                             : (r == 4) ? olf
                                        : orow[r - 5];
                    stv = 0.5f * (cv + mtv);
                    wfac = 0.5f;
                }

                float a = stv, bv = ax;
                float safeb = (fabsf(bv) < 1e-6f) ? 1e-6f : bv;
                float dvv = a / safeb;
                float md  = a - safeb * floorf(dvv);
                float sh  = fminf(fmaxf(bv, 0.0f), 31.0f);
                float eqg = eq_gate_d(a - bv);
                float lt  = sigmoidf_(20.0f * (bv - a - 0.5f));
                float gt  = sigmoidf_(20.0f * (a - bv - 0.5f));
                float outs[15] = {
                    imm, bp + imm, a + bv, a - bv, a * bv, dvv, md,
                    a * exp2f(sh), a * exp2f(-sh),
                    eqg, 1.0f - eqg, lt, gt, 1.0f - gt, 1.0f - lt
                };

                float gsum = 0.0f, acc = 0.0f, pop = 0.0f;
#pragma unroll
                for (int j = 0; j < 15; ++j) {
                    float gg = eq_gate_d(opc - opv[j]);
                    gsum += gg;
                    acc  += gg * outs[j];
                    if (j >= 2) pop += gg;
                }
                float nax = acc + (1.0f - gsum) * ax;

                mrow_out[target] = mtv + pop * wfac * (nax - mtv);

                sp = sp + 8.0f * pop;
                pc = pc + 8.0f;
                ax = nax;
            }
        }
    }
}

extern "C" void kernel_launch(void* const* d_in, const int* in_sizes, int n_in,
                              void* d_out, int out_size, void* d_ws, size_t ws_size,
                              hipStream_t stream) {
    const float* memory = (const float*)d_in[0];
    const float* output = (const float*)d_in[1];
    const float* ax     = (const float*)d_in[2];
    const int*   pc     = (const int*)d_in[3];
    const int*   sp     = (const int*)d_in[4];
    const int*   bp     = (const int*)d_in[5];
    const int*   ol     = (const int*)d_in[6];
    const int*   ns     = (const int*)d_in[7];

    int B = in_sizes[0] / MEMSZ;

    hipLaunchKernelGGL(fused_kernel, dim3(B), dim3(256), 0, stream,
                       memory, output, ax, pc, sp, bp, ol, ns,
                       (float*)d_out, B);
}